// Round 1
// baseline (162.514 us; speedup 1.0000x reference)
//
#include <hip/hip_runtime.h>

typedef __bf16 bf16x8 __attribute__((ext_vector_type(8)));
typedef float f32x4 __attribute__((ext_vector_type(4)));
typedef unsigned short ushort8_t __attribute__((ext_vector_type(8)));
typedef unsigned short ushort_t;

#define D_IN   1024
#define N_ST   16
#define T_LEN  2048
#define B_SZ   2
#define M_ROWS (B_SZ * T_LEN)      /* 4096 */
#define N_COLS (D_IN + 2 * N_ST)   /* 1056 */
#define NCH    64
#define CHL    (T_LEN / NCH)       /* 32 */

/* ---------------- fp32 -> bf16 (RNE) conversion, 8 elems/thread ---------- */
__global__ void cvt_bf16_k(const float* __restrict__ src,
                           ushort_t* __restrict__ dst, int n8) {
    int i = blockIdx.x * blockDim.x + threadIdx.x;
    if (i >= n8) return;
    const float4* s4 = (const float4*)src;
    float4 f0 = s4[2 * i], f1 = s4[2 * i + 1];
    float fv[8] = {f0.x, f0.y, f0.z, f0.w, f1.x, f1.y, f1.z, f1.w};
    ushort8_t o;
#pragma unroll
    for (int j = 0; j < 8; ++j) {
        unsigned ub = __builtin_bit_cast(unsigned, fv[j]);
        ub = (ub + 0x7fffu + ((ub >> 16) & 1u)) >> 16;
        o[j] = (ushort_t)ub;
    }
    *(ushort8_t*)(dst + (size_t)i * 8) = o;
}

/* ---------------- combined projection GEMM (bf16 MFMA) -------------------
   C[4096][1056] = u[4096][1024] * Wcat[1056][1024]^T
   wave tile: 64 rows x 32 cols; 8 mfma_f32_16x16x32_bf16 per K-step of 32.
   epilogue: col<1024 -> dt = softplus(acc + b_dt); else B_ssm / C_ssm.     */
__global__ __launch_bounds__(256) void gemm_proj(
    const ushort_t* __restrict__ u16, const ushort_t* __restrict__ w16,
    const float* __restrict__ b_dt, float* __restrict__ dt,
    float* __restrict__ Bs, float* __restrict__ Cs) {
    int blk = blockIdx.x;            /* 528 = 16 mt-groups * 33 nt */
    int nt  = blk % 33;
    int mtg = blk / 33;
    int wv   = threadIdx.x >> 6;
    int lane = threadIdx.x & 63;
    int mt = mtg * 4 + wv;           /* 0..63 */
    int m0 = mt * 64;
    int n0 = nt * 32;
    int r = lane & 15, g = lane >> 4;

    const ushort_t* ap = u16 + (size_t)(m0 + r) * D_IN + g * 8;
    const ushort_t* bp = w16 + (size_t)(n0 + r) * D_IN + g * 8;

    f32x4 acc[4][2] = {};
    for (int k0 = 0; k0 < D_IN; k0 += 32) {
        bf16x8 a[4], bfr[2];
#pragma unroll
        for (int i = 0; i < 4; ++i)
            a[i] = *(const bf16x8*)(ap + (size_t)i * 16 * D_IN + k0);
#pragma unroll
        for (int i = 0; i < 2; ++i)
            bfr[i] = *(const bf16x8*)(bp + (size_t)i * 16 * D_IN + k0);
#pragma unroll
        for (int mi = 0; mi < 4; ++mi)
#pragma unroll
            for (int ni = 0; ni < 2; ++ni)
                acc[mi][ni] = __builtin_amdgcn_mfma_f32_16x16x32_bf16(
                    a[mi], bfr[ni], acc[mi][ni], 0, 0, 0);
    }
#pragma unroll
    for (int mi = 0; mi < 4; ++mi) {
#pragma unroll
        for (int ni = 0; ni < 2; ++ni) {
            int col = n0 + ni * 16 + r;
#pragma unroll
            for (int q = 0; q < 4; ++q) {
                int row = m0 + mi * 16 + g * 4 + q;
                float v = acc[mi][ni][q];
                if (col < D_IN) {
                    v += b_dt[col];
                    float sp = fmaxf(v, 0.f) + log1pf(__expf(-fabsf(v)));
                    dt[(size_t)row * D_IN + col] = sp;
                } else if (col < D_IN + N_ST) {
                    Bs[(size_t)row * N_ST + (col - D_IN)] = v;
                } else {
                    Cs[(size_t)row * N_ST + (col - D_IN - N_ST)] = v;
                }
            }
        }
    }
}

/* ---------------- scan pass 1: per-chunk local scan ----------------------
   thread = (b, d, chunk); 16 states in regs; outputs P (decay product) and
   S (local final state), layout [b][c][d][n].                              */
__global__ __launch_bounds__(256) void scan_pass1(
    const float* __restrict__ dt, const float* __restrict__ u,
    const float* __restrict__ Bs, const float* __restrict__ logA,
    float* __restrict__ P, float* __restrict__ S) {
    int blk = blockIdx.x;                 /* 512 = 4 dblk * 2 b * 64 c */
    int b = (blk >> 2) & 1, c = blk >> 3;
    int d = ((blk & 3) << 8) + threadIdx.x;

    float A[N_ST];
    {
        const float4* la = (const float4*)(logA + (size_t)d * N_ST);
#pragma unroll
        for (int q = 0; q < 4; ++q) {
            float4 v = la[q];
            A[4 * q + 0] = -expf(v.x); A[4 * q + 1] = -expf(v.y);
            A[4 * q + 2] = -expf(v.z); A[4 * q + 3] = -expf(v.w);
        }
    }
    float x[N_ST], p[N_ST];
#pragma unroll
    for (int n = 0; n < N_ST; ++n) { x[n] = 0.f; p[n] = 1.f; }

    int t0 = c * CHL;
    size_t rowbase = (size_t)(b * T_LEN + t0);
    const float* dtp = dt + rowbase * D_IN + d;
    const float* up  = u  + rowbase * D_IN + d;
    const float4* bsp = (const float4*)(Bs + rowbase * N_ST);

    for (int tt = 0; tt < CHL; ++tt) {
        float dtv = dtp[(size_t)tt * D_IN];
        float uv  = up[(size_t)tt * D_IN];
        float4 b0 = bsp[tt * 4 + 0], b1 = bsp[tt * 4 + 1];
        float4 b2 = bsp[tt * 4 + 2], b3 = bsp[tt * 4 + 3];
        float bv[N_ST] = {b0.x, b0.y, b0.z, b0.w, b1.x, b1.y, b1.z, b1.w,
                          b2.x, b2.y, b2.z, b2.w, b3.x, b3.y, b3.z, b3.w};
        float du = dtv * uv;
#pragma unroll
        for (int n = 0; n < N_ST; ++n) {
            float e = __expf(dtv * A[n]);
            x[n] = e * x[n] + bv[n] * du;
            p[n] *= e;
        }
    }
    size_t base = (((size_t)b * NCH + c) * D_IN + d) * N_ST;
    float4* Sp = (float4*)(S + base);
    float4* Pp = (float4*)(P + base);
#pragma unroll
    for (int q = 0; q < 4; ++q) {
        Sp[q] = make_float4(x[4 * q], x[4 * q + 1], x[4 * q + 2], x[4 * q + 3]);
        Pp[q] = make_float4(p[4 * q], p[4 * q + 1], p[4 * q + 2], p[4 * q + 3]);
    }
}

/* ---------------- chunk combine: serial recurrence over 64 chunks -------- */
__global__ void scan_combine(const float* __restrict__ P,
                             const float* __restrict__ S,
                             float* __restrict__ xst) {
    int tid = blockIdx.x * 256 + threadIdx.x;   /* 32768 */
    int b = tid >> 14, dn = tid & 16383;
    float x = 0.f;
#pragma unroll 8
    for (int c = 0; c < NCH; ++c) {
        size_t idx = (((size_t)b * NCH + c) << 14) + dn;
        xst[idx] = x;
        x = P[idx] * x + S[idx];
    }
}

/* ---------------- scan pass 2: replay chunk from true start, emit y ------ */
__global__ __launch_bounds__(256) void scan_pass2(
    const float* __restrict__ dt, const float* __restrict__ u,
    const float* __restrict__ Bs, const float* __restrict__ Cs,
    const float* __restrict__ logA, const float* __restrict__ xst,
    const float* __restrict__ Dp, float* __restrict__ y) {
    int blk = blockIdx.x;
    int b = (blk >> 2) & 1, c = blk >> 3;
    int d = ((blk & 3) << 8) + threadIdx.x;

    float A[N_ST];
    {
        const float4* la = (const float4*)(logA + (size_t)d * N_ST);
#pragma unroll
        for (int q = 0; q < 4; ++q) {
            float4 v = la[q];
            A[4 * q + 0] = -expf(v.x); A[4 * q + 1] = -expf(v.y);
            A[4 * q + 2] = -expf(v.z); A[4 * q + 3] = -expf(v.w);
        }
    }
    float x[N_ST];
    size_t xbase = (((size_t)b * NCH + c) * D_IN + d) * N_ST;
    {
        const float4* xp = (const float4*)(xst + xbase);
#pragma unroll
        for (int q = 0; q < 4; ++q) {
            float4 v = xp[q];
            x[4 * q + 0] = v.x; x[4 * q + 1] = v.y;
            x[4 * q + 2] = v.z; x[4 * q + 3] = v.w;
        }
    }
    float dpar = Dp[d];

    int t0 = c * CHL;
    size_t rowbase = (size_t)(b * T_LEN + t0);
    const float* dtp = dt + rowbase * D_IN + d;
    const float* up  = u  + rowbase * D_IN + d;
    const float4* bsp = (const float4*)(Bs + rowbase * N_ST);
    const float4* csp = (const float4*)(Cs + rowbase * N_ST);
    float* yp = y + rowbase * D_IN + d;

    for (int tt = 0; tt < CHL; ++tt) {
        float dtv = dtp[(size_t)tt * D_IN];
        float uv  = up[(size_t)tt * D_IN];
        float4 b0 = bsp[tt * 4 + 0], b1 = bsp[tt * 4 + 1];
        float4 b2 = bsp[tt * 4 + 2], b3 = bsp[tt * 4 + 3];
        float4 c0 = csp[tt * 4 + 0], c1 = csp[tt * 4 + 1];
        float4 c2 = csp[tt * 4 + 2], c3 = csp[tt * 4 + 3];
        float bv[N_ST] = {b0.x, b0.y, b0.z, b0.w, b1.x, b1.y, b1.z, b1.w,
                          b2.x, b2.y, b2.z, b2.w, b3.x, b3.y, b3.z, b3.w};
        float cv[N_ST] = {c0.x, c0.y, c0.z, c0.w, c1.x, c1.y, c1.z, c1.w,
                          c2.x, c2.y, c2.z, c2.w, c3.x, c3.y, c3.z, c3.w};
        float du = dtv * uv;
        float yv = uv * dpar;
#pragma unroll
        for (int n = 0; n < N_ST; ++n) {
            float e = __expf(dtv * A[n]);
            x[n] = e * x[n] + bv[n] * du;
            yv += x[n] * cv[n];
        }
        yp[(size_t)tt * D_IN] = yv;
    }
}

/* ------------------------------------------------------------------------ */
extern "C" void kernel_launch(void* const* d_in, const int* in_sizes, int n_in,
                              void* d_out, int out_size, void* d_ws, size_t ws_size,
                              hipStream_t stream) {
    const float* u    = (const float*)d_in[0];
    const float* W_B  = (const float*)d_in[1];
    const float* W_C  = (const float*)d_in[2];
    const float* W_dt = (const float*)d_in[3];
    const float* b_dt = (const float*)d_in[4];
    const float* logA = (const float*)d_in[5];
    const float* Dp   = (const float*)d_in[6];
    float* y = (float*)d_out;

    char* ws = (char*)d_ws;
    ushort_t* u16 = (ushort_t*)(ws);                 /* 8,388,608 B  */
    ushort_t* w16 = (ushort_t*)(ws + 8388608);       /* 2,162,688 B  */
    float* dt  = (float*)(ws + 10551296);            /* 16,777,216 B */
    float* Bs  = (float*)(ws + 27328512);            /* 262,144 B    */
    float* Cs  = (float*)(ws + 27590656);            /* 262,144 B    */
    float* P   = (float*)(ws + 27852800);            /* 8,388,608 B  */
    float* S   = (float*)(ws + 36241408);            /* 8,388,608 B  */
    float* xst = (float*)(ws + 44630016);            /* 8,388,608 B  */

    cvt_bf16_k<<<2048, 256, 0, stream>>>(u, u16, M_ROWS * D_IN / 8);
    cvt_bf16_k<<<512, 256, 0, stream>>>(W_dt, w16, D_IN * D_IN / 8);
    cvt_bf16_k<<<8, 256, 0, stream>>>(W_B, w16 + (size_t)D_IN * D_IN, N_ST * D_IN / 8);
    cvt_bf16_k<<<8, 256, 0, stream>>>(W_C, w16 + (size_t)(D_IN + N_ST) * D_IN, N_ST * D_IN / 8);

    gemm_proj<<<528, 256, 0, stream>>>(u16, w16, b_dt, dt, Bs, Cs);

    scan_pass1<<<512, 256, 0, stream>>>(dt, u, Bs, logA, P, S);
    scan_combine<<<128, 256, 0, stream>>>(P, S, xst);
    scan_pass2<<<512, 256, 0, stream>>>(dt, u, Bs, Cs, logA, xst, Dp, y);
}

// Round 2
// 141.188 us; speedup vs baseline: 1.1510x; 1.1510x over previous
//
#include <hip/hip_runtime.h>

typedef __bf16 bf16x8 __attribute__((ext_vector_type(8)));
typedef float f32x4 __attribute__((ext_vector_type(4)));
typedef unsigned short ushort8_t __attribute__((ext_vector_type(8)));
typedef unsigned short ushort_t;

#define D_IN   1024
#define N_ST   16
#define T_LEN  2048
#define B_SZ   2
#define M_ROWS (B_SZ * T_LEN)      /* 4096 */
#define N_REAL (D_IN + 2 * N_ST)   /* 1056 */
#define N_PAD  1152                /* 9 col-tiles of 128 (pad rows are zero) */
#define NCH    64
#define CHL    (T_LEN / NCH)       /* 32 */

#define GLB(p) ((const __attribute__((address_space(1))) void*)(p))
#define LDS(p) ((__attribute__((address_space(3))) void*)(p))

/* ---------------- fp32 -> bf16 (RNE), 8 elems/thread --------------------- */
__global__ void cvt_bf16_k(const float* __restrict__ src,
                           ushort_t* __restrict__ dst, int n8) {
    int i = blockIdx.x * blockDim.x + threadIdx.x;
    if (i >= n8) return;
    const float4* s4 = (const float4*)src;
    float4 f0 = s4[2 * i], f1 = s4[2 * i + 1];
    float fv[8] = {f0.x, f0.y, f0.z, f0.w, f1.x, f1.y, f1.z, f1.w};
    ushort8_t o;
#pragma unroll
    for (int j = 0; j < 8; ++j) {
        unsigned ub = __builtin_bit_cast(unsigned, fv[j]);
        ub = (ub + 0x7fffu + ((ub >> 16) & 1u)) >> 16;
        o[j] = (ushort_t)ub;
    }
    *(ushort8_t*)(dst + (size_t)i * 8) = o;
}

/* ---------------- W_dt|W_B|W_C -> padded bf16 [1152][1024] --------------- */
__global__ void cvt_w_k(const float* __restrict__ Wdt, const float* __restrict__ WB,
                        const float* __restrict__ WC, ushort_t* __restrict__ dst) {
    int i = blockIdx.x * 256 + threadIdx.x;      /* 147456 threads, 8 elems each */
    int row = i >> 7;
    ushort8_t o = (ushort8_t)0;
    const float* src = nullptr;
    size_t off = 0;
    if (row < D_IN)            { src = Wdt; off = (size_t)i * 8; }
    else if (row < D_IN + N_ST){ src = WB;  off = (size_t)i * 8 - (size_t)D_IN * D_IN; }
    else if (row < N_REAL)     { src = WC;  off = (size_t)i * 8 - (size_t)(D_IN + N_ST) * D_IN; }
    if (src) {
        const float4* s4 = (const float4*)(src + off);
        float4 f0 = s4[0], f1 = s4[1];
        float fv[8] = {f0.x, f0.y, f0.z, f0.w, f1.x, f1.y, f1.z, f1.w};
#pragma unroll
        for (int j = 0; j < 8; ++j) {
            unsigned ub = __builtin_bit_cast(unsigned, fv[j]);
            ub = (ub + 0x7fffu + ((ub >> 16) & 1u)) >> 16;
            o[j] = (ushort_t)ub;
        }
    }
    *(ushort8_t*)(dst + (size_t)i * 8) = o;
}

/* ---------------- fused projection GEMM, m97 structure + 2-phase ---------
   C[4096][1152] = u16[4096][1024] * w16[1152][1024]^T
   128x128 tile, BK=32, 4 waves x (64x64 = 4x4 frags), global_load_lds w=16,
   double-buffered LDS: stage(next) -> compute(cur) -> barrier.
   epilogue routes col: <1024 dt=softplus(+b_dt); <1040 B; <1056 C; else pad */
__global__ __launch_bounds__(256) void gemm_proj(
    const ushort_t* __restrict__ u16, const ushort_t* __restrict__ w16,
    const float* __restrict__ b_dt, float* __restrict__ dt,
    float* __restrict__ Bsm, float* __restrict__ Csm) {
    __shared__ ushort_t As[2][128 * 32];
    __shared__ ushort_t Bs[2][128 * 32];
    int bm = blockIdx.x & 31, bn = blockIdx.x >> 5;
    int m0 = bm << 7, n0 = bn << 7;
    int t = threadIdx.x, wid = t >> 6;
    int lane = t & 63, r = lane & 15, g = lane >> 4;
    int wr = wid >> 1, wc = wid & 1;

    const ushort_t* gA = u16 + (size_t)(m0 + (t >> 2)) * D_IN + (t & 3) * 8;
    const ushort_t* gB = w16 + (size_t)(n0 + (t >> 2)) * D_IN + (t & 3) * 8;

    f32x4 acc[4][4] = {};

#define STAGE(buf, k0)                                                         \
    do {                                                                       \
        __builtin_amdgcn_global_load_lds(GLB(gA + (k0)),                       \
            LDS((char*)&As[buf][0] + wid * 1024), 16, 0, 0);                   \
        __builtin_amdgcn_global_load_lds(GLB(gA + (size_t)64 * D_IN + (k0)),   \
            LDS((char*)&As[buf][0] + 4096 + wid * 1024), 16, 0, 0);            \
        __builtin_amdgcn_global_load_lds(GLB(gB + (k0)),                       \
            LDS((char*)&Bs[buf][0] + wid * 1024), 16, 0, 0);                   \
        __builtin_amdgcn_global_load_lds(GLB(gB + (size_t)64 * D_IN + (k0)),   \
            LDS((char*)&Bs[buf][0] + 4096 + wid * 1024), 16, 0, 0);            \
    } while (0)

    STAGE(0, 0);
    __syncthreads();
    for (int ks = 0; ks < 32; ++ks) {
        int cur = ks & 1;
        if (ks < 31) STAGE(cur ^ 1, (ks + 1) * 32);   /* prefetch next tile */
        const ushort_t* fa = &As[cur][(wr * 64 + r) * 32 + g * 8];
        const ushort_t* fb = &Bs[cur][(wc * 64 + r) * 32 + g * 8];
        bf16x8 a[4], b[4];
#pragma unroll
        for (int i = 0; i < 4; ++i) a[i] = *(const bf16x8*)(fa + i * 16 * 32);
#pragma unroll
        for (int i = 0; i < 4; ++i) b[i] = *(const bf16x8*)(fb + i * 16 * 32);
#pragma unroll
        for (int mi = 0; mi < 4; ++mi)
#pragma unroll
            for (int ni = 0; ni < 4; ++ni)
                acc[mi][ni] = __builtin_amdgcn_mfma_f32_16x16x32_bf16(
                    a[mi], b[ni], acc[mi][ni], 0, 0, 0);
        __syncthreads();   /* drains vmcnt(0) AFTER compute covered latency */
    }
#undef STAGE

#pragma unroll
    for (int mi = 0; mi < 4; ++mi)
#pragma unroll
        for (int ni = 0; ni < 4; ++ni) {
            int col = n0 + wc * 64 + ni * 16 + r;
#pragma unroll
            for (int q = 0; q < 4; ++q) {
                int row = m0 + wr * 64 + mi * 16 + g * 4 + q;
                float v = acc[mi][ni][q];
                if (col < D_IN) {
                    v += b_dt[col];
                    float sp = fmaxf(v, 0.f) + log1pf(__expf(-fabsf(v)));
                    dt[(size_t)row * D_IN + col] = sp;
                } else if (col < D_IN + N_ST) {
                    Bsm[(size_t)row * N_ST + (col - D_IN)] = v;
                } else if (col < N_REAL) {
                    Csm[(size_t)row * N_ST + (col - D_IN - N_ST)] = v;
                }
            }
        }
}

/* ---------------- scan pass 1: per-chunk local scan ---------------------- */
__global__ __launch_bounds__(256) void scan_pass1(
    const float* __restrict__ dt, const float* __restrict__ u,
    const float* __restrict__ Bs, const float* __restrict__ logA,
    float* __restrict__ P, float* __restrict__ S) {
    int blk = blockIdx.x;                 /* 512 = 4 dblk * 2 b * 64 c */
    int b = (blk >> 2) & 1, c = blk >> 3;
    int d = ((blk & 3) << 8) + threadIdx.x;

    float A[N_ST];
    {
        const float4* la = (const float4*)(logA + (size_t)d * N_ST);
#pragma unroll
        for (int q = 0; q < 4; ++q) {
            float4 v = la[q];
            A[4 * q + 0] = -expf(v.x); A[4 * q + 1] = -expf(v.y);
            A[4 * q + 2] = -expf(v.z); A[4 * q + 3] = -expf(v.w);
        }
    }
    float x[N_ST], p[N_ST];
#pragma unroll
    for (int n = 0; n < N_ST; ++n) { x[n] = 0.f; p[n] = 1.f; }

    int t0 = c * CHL;
    size_t rowbase = (size_t)(b * T_LEN + t0);
    const float* dtp = dt + rowbase * D_IN + d;
    const float* up  = u  + rowbase * D_IN + d;
    const float4* bsp = (const float4*)(Bs + rowbase * N_ST);

    for (int tt = 0; tt < CHL; ++tt) {
        float dtv = dtp[(size_t)tt * D_IN];
        float uv  = up[(size_t)tt * D_IN];
        float4 b0 = bsp[tt * 4 + 0], b1 = bsp[tt * 4 + 1];
        float4 b2 = bsp[tt * 4 + 2], b3 = bsp[tt * 4 + 3];
        float bv[N_ST] = {b0.x, b0.y, b0.z, b0.w, b1.x, b1.y, b1.z, b1.w,
                          b2.x, b2.y, b2.z, b2.w, b3.x, b3.y, b3.z, b3.w};
        float du = dtv * uv;
#pragma unroll
        for (int n = 0; n < N_ST; ++n) {
            float e = __expf(dtv * A[n]);
            x[n] = e * x[n] + bv[n] * du;
            p[n] *= e;
        }
    }
    size_t base = (((size_t)b * NCH + c) * D_IN + d) * N_ST;
    float4* Sp = (float4*)(S + base);
    float4* Pp = (float4*)(P + base);
#pragma unroll
    for (int q = 0; q < 4; ++q) {
        Sp[q] = make_float4(x[4 * q], x[4 * q + 1], x[4 * q + 2], x[4 * q + 3]);
        Pp[q] = make_float4(p[4 * q], p[4 * q + 1], p[4 * q + 2], p[4 * q + 3]);
    }
}

/* ---------------- chunk combine: serial recurrence over 64 chunks -------- */
__global__ void scan_combine(const float* __restrict__ P,
                             const float* __restrict__ S,
                             float* __restrict__ xst) {
    int tid = blockIdx.x * 256 + threadIdx.x;   /* 32768 */
    int b = tid >> 14, dn = tid & 16383;
    float x = 0.f;
#pragma unroll 8
    for (int c = 0; c < NCH; ++c) {
        size_t idx = (((size_t)b * NCH + c) << 14) + dn;
        xst[idx] = x;
        x = P[idx] * x + S[idx];
    }
}

/* ---------------- scan pass 2: replay chunk from true start, emit y ------ */
__global__ __launch_bounds__(256) void scan_pass2(
    const float* __restrict__ dt, const float* __restrict__ u,
    const float* __restrict__ Bs, const float* __restrict__ Cs,
    const float* __restrict__ logA, const float* __restrict__ xst,
    const float* __restrict__ Dp, float* __restrict__ y) {
    int blk = blockIdx.x;
    int b = (blk >> 2) & 1, c = blk >> 3;
    int d = ((blk & 3) << 8) + threadIdx.x;

    float A[N_ST];
    {
        const float4* la = (const float4*)(logA + (size_t)d * N_ST);
#pragma unroll
        for (int q = 0; q < 4; ++q) {
            float4 v = la[q];
            A[4 * q + 0] = -expf(v.x); A[4 * q + 1] = -expf(v.y);
            A[4 * q + 2] = -expf(v.z); A[4 * q + 3] = -expf(v.w);
        }
    }
    float x[N_ST];
    size_t xbase = (((size_t)b * NCH + c) * D_IN + d) * N_ST;
    {
        const float4* xp = (const float4*)(xst + xbase);
#pragma unroll
        for (int q = 0; q < 4; ++q) {
            float4 v = xp[q];
            x[4 * q + 0] = v.x; x[4 * q + 1] = v.y;
            x[4 * q + 2] = v.z; x[4 * q + 3] = v.w;
        }
    }
    float dpar = Dp[d];

    int t0 = c * CHL;
    size_t rowbase = (size_t)(b * T_LEN + t0);
    const float* dtp = dt + rowbase * D_IN + d;
    const float* up  = u  + rowbase * D_IN + d;
    const float4* bsp = (const float4*)(Bs + rowbase * N_ST);
    const float4* csp = (const float4*)(Cs + rowbase * N_ST);
    float* yp = y + rowbase * D_IN + d;

    for (int tt = 0; tt < CHL; ++tt) {
        float dtv = dtp[(size_t)tt * D_IN];
        float uv  = up[(size_t)tt * D_IN];
        float4 b0 = bsp[tt * 4 + 0], b1 = bsp[tt * 4 + 1];
        float4 b2 = bsp[tt * 4 + 2], b3 = bsp[tt * 4 + 3];
        float4 c0 = csp[tt * 4 + 0], c1 = csp[tt * 4 + 1];
        float4 c2 = csp[tt * 4 + 2], c3 = csp[tt * 4 + 3];
        float bv[N_ST] = {b0.x, b0.y, b0.z, b0.w, b1.x, b1.y, b1.z, b1.w,
                          b2.x, b2.y, b2.z, b2.w, b3.x, b3.y, b3.z, b3.w};
        float cv[N_ST] = {c0.x, c0.y, c0.z, c0.w, c1.x, c1.y, c1.z, c1.w,
                          c2.x, c2.y, c2.z, c2.w, c3.x, c3.y, c3.z, c3.w};
        float du = dtv * uv;
        float yv = uv * dpar;
#pragma unroll
        for (int n = 0; n < N_ST; ++n) {
            float e = __expf(dtv * A[n]);
            x[n] = e * x[n] + bv[n] * du;
            yv += x[n] * cv[n];
        }
        yp[(size_t)tt * D_IN] = yv;
    }
}

/* ------------------------------------------------------------------------ */
extern "C" void kernel_launch(void* const* d_in, const int* in_sizes, int n_in,
                              void* d_out, int out_size, void* d_ws, size_t ws_size,
                              hipStream_t stream) {
    const float* u    = (const float*)d_in[0];
    const float* W_B  = (const float*)d_in[1];
    const float* W_C  = (const float*)d_in[2];
    const float* W_dt = (const float*)d_in[3];
    const float* b_dt = (const float*)d_in[4];
    const float* logA = (const float*)d_in[5];
    const float* Dp   = (const float*)d_in[6];
    float* y = (float*)d_out;

    char* ws = (char*)d_ws;
    ushort_t* u16 = (ushort_t*)(ws);                 /* 8,388,608 B  */
    ushort_t* w16 = (ushort_t*)(ws + 8388608);       /* 2,359,296 B  */
    float* dt  = (float*)(ws + 10747904);            /* 16,777,216 B */
    float* Bs  = (float*)(ws + 27525120);            /* 262,144 B    */
    float* Cs  = (float*)(ws + 27787264);            /* 262,144 B    */
    float* P   = (float*)(ws + 28049408);            /* 8,388,608 B  */
    float* S   = (float*)(ws + 36438016);            /* 8,388,608 B  */
    float* xst = (float*)(ws + 44826624);            /* 8,388,608 B  */

    cvt_bf16_k<<<2048, 256, 0, stream>>>(u, u16, M_ROWS * D_IN / 8);
    cvt_w_k<<<576, 256, 0, stream>>>(W_dt, W_B, W_C, w16);

    gemm_proj<<<288, 256, 0, stream>>>(u16, w16, b_dt, dt, Bs, Cs);

    scan_pass1<<<512, 256, 0, stream>>>(dt, u, Bs, logA, P, S);
    scan_combine<<<128, 256, 0, stream>>>(P, S, xst);
    scan_pass2<<<512, 256, 0, stream>>>(dt, u, Bs, Cs, logA, xst, Dp, y);
}

// Round 3
// 90.374 us; speedup vs baseline: 1.7982x; 1.5623x over previous
//
#include <hip/hip_runtime.h>

typedef __bf16 bf16x8 __attribute__((ext_vector_type(8)));
typedef float f32x4 __attribute__((ext_vector_type(4)));
typedef unsigned short ushort8_t __attribute__((ext_vector_type(8)));
typedef unsigned short ushort_t;

#define D_IN   1024
#define N_ST   16
#define T_LEN  2048
#define B_SZ   2
#define M_ROWS (B_SZ * T_LEN)      /* 4096 */
#define N_REAL (D_IN + 2 * N_ST)   /* 1056 */
#define N_PAD  1152                /* 18 col-tiles of 64 (pad rows are zero) */
#define NCH    64
#define CHL    (T_LEN / NCH)       /* 32 */

#define GLB(p) ((const __attribute__((address_space(1))) void*)(p))
#define LDS(p) ((__attribute__((address_space(3))) void*)(p))

/* ---------------- fp32 -> bf16 (RNE), 8 elems/thread --------------------- */
__global__ void cvt_bf16_k(const float* __restrict__ src,
                           ushort_t* __restrict__ dst, int n8) {
    int i = blockIdx.x * blockDim.x + threadIdx.x;
    if (i >= n8) return;
    const float4* s4 = (const float4*)src;
    float4 f0 = s4[2 * i], f1 = s4[2 * i + 1];
    float fv[8] = {f0.x, f0.y, f0.z, f0.w, f1.x, f1.y, f1.z, f1.w};
    ushort8_t o;
#pragma unroll
    for (int j = 0; j < 8; ++j) {
        unsigned ub = __builtin_bit_cast(unsigned, fv[j]);
        ub = (ub + 0x7fffu + ((ub >> 16) & 1u)) >> 16;
        o[j] = (ushort_t)ub;
    }
    *(ushort8_t*)(dst + (size_t)i * 8) = o;
}

/* ---------------- W_dt|W_B|W_C -> padded bf16 [1152][1024] --------------- */
__global__ void cvt_w_k(const float* __restrict__ Wdt, const float* __restrict__ WB,
                        const float* __restrict__ WC, ushort_t* __restrict__ dst) {
    int i = blockIdx.x * 256 + threadIdx.x;      /* 147456 threads, 8 elems each */
    int row = i >> 7;
    ushort8_t o = (ushort8_t)0;
    const float* src = nullptr;
    size_t off = 0;
    if (row < D_IN)            { src = Wdt; off = (size_t)i * 8; }
    else if (row < D_IN + N_ST){ src = WB;  off = (size_t)i * 8 - (size_t)D_IN * D_IN; }
    else if (row < N_REAL)     { src = WC;  off = (size_t)i * 8 - (size_t)(D_IN + N_ST) * D_IN; }
    if (src) {
        const float4* s4 = (const float4*)(src + off);
        float4 f0 = s4[0], f1 = s4[1];
        float fv[8] = {f0.x, f0.y, f0.z, f0.w, f1.x, f1.y, f1.z, f1.w};
#pragma unroll
        for (int j = 0; j < 8; ++j) {
            unsigned ub = __builtin_bit_cast(unsigned, fv[j]);
            ub = (ub + 0x7fffu + ((ub >> 16) & 1u)) >> 16;
            o[j] = (ushort_t)ub;
        }
    }
    *(ushort8_t*)(dst + (size_t)i * 8) = o;
}

/* ---------------- fused projection GEMM: 64x64 tile, 1152 blocks ---------
   C[4096][1152] = u16[4096][1024] * w16[1152][1024]^T
   4 waves x (32x32 = 2x2 frags), BK=32, global_load_lds w=16, dbuf LDS.
   Many small blocks (4.5/CU) -> implicit wave-level overlap hides barrier
   drain (m114). epilogue: col<1024 dt=softplus(+b_dt); <1040 B; <1056 C.  */
__global__ __launch_bounds__(256) void gemm_proj(
    const ushort_t* __restrict__ u16, const ushort_t* __restrict__ w16,
    const float* __restrict__ b_dt, float* __restrict__ dt,
    float* __restrict__ Bsm, float* __restrict__ Csm) {
    __shared__ ushort_t As[2][64 * 32];
    __shared__ ushort_t Bs[2][64 * 32];
    int bm = blockIdx.x & 63, bn = blockIdx.x >> 6;
    int m0 = bm << 6, n0 = bn << 6;
    int t = threadIdx.x, wid = t >> 6;
    int lane = t & 63, r = lane & 15, g = lane >> 4;
    int wr = wid >> 1, wc = wid & 1;

    const ushort_t* gA = u16 + (size_t)(m0 + (t >> 2)) * D_IN + (t & 3) * 8;
    const ushort_t* gB = w16 + (size_t)(n0 + (t >> 2)) * D_IN + (t & 3) * 8;

    f32x4 acc[2][2] = {};

#define STAGE(buf, k0)                                                         \
    do {                                                                       \
        __builtin_amdgcn_global_load_lds(GLB(gA + (k0)),                       \
            LDS((char*)&As[buf][0] + wid * 1024), 16, 0, 0);                   \
        __builtin_amdgcn_global_load_lds(GLB(gB + (k0)),                       \
            LDS((char*)&Bs[buf][0] + wid * 1024), 16, 0, 0);                   \
    } while (0)

    STAGE(0, 0);
    __syncthreads();
    for (int ks = 0; ks < 32; ++ks) {
        int cur = ks & 1;
        if (ks < 31) STAGE(cur ^ 1, (ks + 1) * 32);   /* prefetch next tile */
        const ushort_t* fa = &As[cur][(wr * 32 + r) * 32 + g * 8];
        const ushort_t* fb = &Bs[cur][(wc * 32 + r) * 32 + g * 8];
        bf16x8 a[2], b[2];
        a[0] = *(const bf16x8*)(fa);
        a[1] = *(const bf16x8*)(fa + 16 * 32);
        b[0] = *(const bf16x8*)(fb);
        b[1] = *(const bf16x8*)(fb + 16 * 32);
#pragma unroll
        for (int mi = 0; mi < 2; ++mi)
#pragma unroll
            for (int ni = 0; ni < 2; ++ni)
                acc[mi][ni] = __builtin_amdgcn_mfma_f32_16x16x32_bf16(
                    a[mi], b[ni], acc[mi][ni], 0, 0, 0);
        __syncthreads();   /* drain lands after compute covered latency */
    }
#undef STAGE

#pragma unroll
    for (int mi = 0; mi < 2; ++mi)
#pragma unroll
        for (int ni = 0; ni < 2; ++ni) {
            int col = n0 + wc * 32 + ni * 16 + r;
#pragma unroll
            for (int q = 0; q < 4; ++q) {
                int row = m0 + wr * 32 + mi * 16 + g * 4 + q;
                float v = acc[mi][ni][q];
                if (col < D_IN) {
                    v += b_dt[col];
                    float sp = fmaxf(v, 0.f) + __logf(1.f + __expf(-fabsf(v)));
                    dt[(size_t)row * D_IN + col] = sp;
                } else if (col < D_IN + N_ST) {
                    Bsm[(size_t)row * N_ST + (col - D_IN)] = v;
                } else if (col < N_REAL) {
                    Csm[(size_t)row * N_ST + (col - D_IN - N_ST)] = v;
                }
            }
        }
}

/* ---------------- scan pass 1: per-chunk local scan ----------------------
   P computed analytically at chunk end: P[n] = exp(A[n] * sum_t dt).       */
__global__ __launch_bounds__(256) void scan_pass1(
    const float* __restrict__ dt, const float* __restrict__ u,
    const float* __restrict__ Bs, const float* __restrict__ logA,
    float* __restrict__ P, float* __restrict__ S) {
    int blk = blockIdx.x;                 /* 512 = 4 dblk * 2 b * 64 c */
    int b = (blk >> 2) & 1, c = blk >> 3;
    int d = ((blk & 3) << 8) + threadIdx.x;

    float A[N_ST];
    {
        const float4* la = (const float4*)(logA + (size_t)d * N_ST);
#pragma unroll
        for (int q = 0; q < 4; ++q) {
            float4 v = la[q];
            A[4 * q + 0] = -expf(v.x); A[4 * q + 1] = -expf(v.y);
            A[4 * q + 2] = -expf(v.z); A[4 * q + 3] = -expf(v.w);
        }
    }
    float x[N_ST];
#pragma unroll
    for (int n = 0; n < N_ST; ++n) x[n] = 0.f;
    float sdt = 0.f;

    int t0 = c * CHL;
    size_t rowbase = (size_t)(b * T_LEN + t0);
    const float* dtp = dt + rowbase * D_IN + d;
    const float* up  = u  + rowbase * D_IN + d;
    const float4* bsp = (const float4*)(Bs + rowbase * N_ST);

    for (int tt = 0; tt < CHL; ++tt) {
        float dtv = dtp[(size_t)tt * D_IN];
        float uv  = up[(size_t)tt * D_IN];
        float4 b0 = bsp[tt * 4 + 0], b1 = bsp[tt * 4 + 1];
        float4 b2 = bsp[tt * 4 + 2], b3 = bsp[tt * 4 + 3];
        float bv[N_ST] = {b0.x, b0.y, b0.z, b0.w, b1.x, b1.y, b1.z, b1.w,
                          b2.x, b2.y, b2.z, b2.w, b3.x, b3.y, b3.z, b3.w};
        float du = dtv * uv;
        sdt += dtv;
#pragma unroll
        for (int n = 0; n < N_ST; ++n) {
            float e = __expf(dtv * A[n]);
            x[n] = e * x[n] + bv[n] * du;
        }
    }
    size_t base = (((size_t)b * NCH + c) * D_IN + d) * N_ST;
    float4* Sp = (float4*)(S + base);
    float4* Pp = (float4*)(P + base);
#pragma unroll
    for (int q = 0; q < 4; ++q) {
        Sp[q] = make_float4(x[4 * q], x[4 * q + 1], x[4 * q + 2], x[4 * q + 3]);
        Pp[q] = make_float4(__expf(A[4 * q] * sdt), __expf(A[4 * q + 1] * sdt),
                            __expf(A[4 * q + 2] * sdt), __expf(A[4 * q + 3] * sdt));
    }
}

/* ---------------- chunk combine: serial recurrence over 64 chunks -------- */
__global__ void scan_combine(const float* __restrict__ P,
                             const float* __restrict__ S,
                             float* __restrict__ xst) {
    int tid = blockIdx.x * 256 + threadIdx.x;   /* 32768 */
    int b = tid >> 14, dn = tid & 16383;
    float x = 0.f;
#pragma unroll 8
    for (int c = 0; c < NCH; ++c) {
        size_t idx = (((size_t)b * NCH + c) << 14) + dn;
        xst[idx] = x;
        x = P[idx] * x + S[idx];
    }
}

/* ---------------- scan pass 2: replay chunk from true start, emit y ------ */
__global__ __launch_bounds__(256) void scan_pass2(
    const float* __restrict__ dt, const float* __restrict__ u,
    const float* __restrict__ Bs, const float* __restrict__ Cs,
    const float* __restrict__ logA, const float* __restrict__ xst,
    const float* __restrict__ Dp, float* __restrict__ y) {
    int blk = blockIdx.x;
    int b = (blk >> 2) & 1, c = blk >> 3;
    int d = ((blk & 3) << 8) + threadIdx.x;

    float A[N_ST];
    {
        const float4* la = (const float4*)(logA + (size_t)d * N_ST);
#pragma unroll
        for (int q = 0; q < 4; ++q) {
            float4 v = la[q];
            A[4 * q + 0] = -expf(v.x); A[4 * q + 1] = -expf(v.y);
            A[4 * q + 2] = -expf(v.z); A[4 * q + 3] = -expf(v.w);
        }
    }
    float x[N_ST];
    size_t xbase = (((size_t)b * NCH + c) * D_IN + d) * N_ST;
    {
        const float4* xp = (const float4*)(xst + xbase);
#pragma unroll
        for (int q = 0; q < 4; ++q) {
            float4 v = xp[q];
            x[4 * q + 0] = v.x; x[4 * q + 1] = v.y;
            x[4 * q + 2] = v.z; x[4 * q + 3] = v.w;
        }
    }
    float dpar = Dp[d];

    int t0 = c * CHL;
    size_t rowbase = (size_t)(b * T_LEN + t0);
    const float* dtp = dt + rowbase * D_IN + d;
    const float* up  = u  + rowbase * D_IN + d;
    const float4* bsp = (const float4*)(Bs + rowbase * N_ST);
    const float4* csp = (const float4*)(Cs + rowbase * N_ST);
    float* yp = y + rowbase * D_IN + d;

    for (int tt = 0; tt < CHL; ++tt) {
        float dtv = dtp[(size_t)tt * D_IN];
        float uv  = up[(size_t)tt * D_IN];
        float4 b0 = bsp[tt * 4 + 0], b1 = bsp[tt * 4 + 1];
        float4 b2 = bsp[tt * 4 + 2], b3 = bsp[tt * 4 + 3];
        float4 c0 = csp[tt * 4 + 0], c1 = csp[tt * 4 + 1];
        float4 c2 = csp[tt * 4 + 2], c3 = csp[tt * 4 + 3];
        float bv[N_ST] = {b0.x, b0.y, b0.z, b0.w, b1.x, b1.y, b1.z, b1.w,
                          b2.x, b2.y, b2.z, b2.w, b3.x, b3.y, b3.z, b3.w};
        float cv[N_ST] = {c0.x, c0.y, c0.z, c0.w, c1.x, c1.y, c1.z, c1.w,
                          c2.x, c2.y, c2.z, c2.w, c3.x, c3.y, c3.z, c3.w};
        float du = dtv * uv;
        float yv = uv * dpar;
#pragma unroll
        for (int n = 0; n < N_ST; ++n) {
            float e = __expf(dtv * A[n]);
            x[n] = e * x[n] + bv[n] * du;
            yv += x[n] * cv[n];
        }
        yp[(size_t)tt * D_IN] = yv;
    }
}

/* ------------------------------------------------------------------------ */
extern "C" void kernel_launch(void* const* d_in, const int* in_sizes, int n_in,
                              void* d_out, int out_size, void* d_ws, size_t ws_size,
                              hipStream_t stream) {
    const float* u    = (const float*)d_in[0];
    const float* W_B  = (const float*)d_in[1];
    const float* W_C  = (const float*)d_in[2];
    const float* W_dt = (const float*)d_in[3];
    const float* b_dt = (const float*)d_in[4];
    const float* logA = (const float*)d_in[5];
    const float* Dp   = (const float*)d_in[6];
    float* y = (float*)d_out;

    char* ws = (char*)d_ws;
    ushort_t* u16 = (ushort_t*)(ws);                 /* 8,388,608 B  */
    ushort_t* w16 = (ushort_t*)(ws + 8388608);       /* 2,359,296 B  */
    float* dt  = (float*)(ws + 10747904);            /* 16,777,216 B */
    float* Bs  = (float*)(ws + 27525120);            /* 262,144 B    */
    float* Cs  = (float*)(ws + 27787264);            /* 262,144 B    */
    float* P   = (float*)(ws + 28049408);            /* 8,388,608 B  */
    float* S   = (float*)(ws + 36438016);            /* 8,388,608 B  */
    float* xst = (float*)(ws + 44826624);            /* 8,388,608 B  */

    cvt_bf16_k<<<2048, 256, 0, stream>>>(u, u16, M_ROWS * D_IN / 8);
    cvt_w_k<<<576, 256, 0, stream>>>(W_dt, W_B, W_C, w16);

    gemm_proj<<<1152, 256, 0, stream>>>(u16, w16, b_dt, dt, Bs, Cs);

    scan_pass1<<<512, 256, 0, stream>>>(dt, u, Bs, logA, P, S);
    scan_combine<<<128, 256, 0, stream>>>(P, S, xst);
    scan_pass2<<<512, 256, 0, stream>>>(dt, u, Bs, Cs, logA, xst, Dp, y);
}